// Round 1
// 1463.486 us; speedup vs baseline: 1.3048x; 1.3048x over previous
//
#include <hip/hip_runtime.h>
#include <math.h>

#define HH 256
#define WW 256
#define CC 64
#define PLANE (HH*WW)

// ---------------- conv 3x3 reflect, direct-global, register-blocked ----------------
// thread = 8 horizontal pixels x 8 output channels; block = 32x8 threads = 256x8 px
// weights read via wave-uniform addresses -> s_load (scalar pipe, free vs VALU)
__global__ __launch_bounds__(256) void conv3x3_kernel(
    const float* __restrict__ in,    // [B,C,H,W]
    const float* __restrict__ w,     // [OC,IC,3,3]
    const float* __restrict__ bias,  // [OC]
    const float* __restrict__ prelu, // [OC] or null
    float* __restrict__ out,         // [B,OC,H,W]
    int do_prelu)
{
    const int tid = threadIdx.x;
    const int tx  = tid & 31;
    const int ty  = tid >> 5;
    const int x0  = tx << 3;                 // 0,8,...,248
    const int y   = (blockIdx.x << 3) + ty;  // 0..255
    const int ocg = blockIdx.y;              // 0..7 -> oc base ocg*8
    const int b   = blockIdx.z;

    // reflect-resolved neighbor rows / edge columns (computed ONCE, no per-ic branching)
    const int ym   = (y  == 0)   ? 1   : y - 1;
    const int yp   = (y  == 255) ? 254 : y + 1;
    const int colL = (x0 == 0)   ? 1   : x0 - 1;   // column x0-1 reflected
    const int colR = (x0 == 248) ? 254 : x0 + 8;   // column x0+8 reflected

    const int rA = ym * WW, rB = y * WW, rC = yp * WW;

    float acc[8][8];
#pragma unroll
    for (int i = 0; i < 8; i++)
#pragma unroll
        for (int j = 0; j < 8; j++) acc[i][j] = 0.f;

    const float* pin   = in + (size_t)b * CC * PLANE;
    const float* wbase = w + (size_t)(ocg * 8) * CC * 9;

    for (int ic = 0; ic < CC; ic++) {
        const float* p = pin + (size_t)ic * PLANE;

        // 3 rows x 10 cols window: 2 aligned float4 + 2 scalar edge loads per row
        float win[3][10];
        {
            const float4 a0 = *(const float4*)(p + rA + x0);
            const float4 a1 = *(const float4*)(p + rA + x0 + 4);
            const float4 b0 = *(const float4*)(p + rB + x0);
            const float4 b1 = *(const float4*)(p + rB + x0 + 4);
            const float4 c0 = *(const float4*)(p + rC + x0);
            const float4 c1 = *(const float4*)(p + rC + x0 + 4);
            win[0][0] = p[rA + colL];
            win[0][1] = a0.x; win[0][2] = a0.y; win[0][3] = a0.z; win[0][4] = a0.w;
            win[0][5] = a1.x; win[0][6] = a1.y; win[0][7] = a1.z; win[0][8] = a1.w;
            win[0][9] = p[rA + colR];
            win[1][0] = p[rB + colL];
            win[1][1] = b0.x; win[1][2] = b0.y; win[1][3] = b0.z; win[1][4] = b0.w;
            win[1][5] = b1.x; win[1][6] = b1.y; win[1][7] = b1.z; win[1][8] = b1.w;
            win[1][9] = p[rB + colR];
            win[2][0] = p[rC + colL];
            win[2][1] = c0.x; win[2][2] = c0.y; win[2][3] = c0.z; win[2][4] = c0.w;
            win[2][5] = c1.x; win[2][6] = c1.y; win[2][7] = c1.z; win[2][8] = c1.w;
            win[2][9] = p[rC + colR];
        }

        const float* wic = wbase + (size_t)ic * 9;
#pragma unroll
        for (int oc = 0; oc < 8; oc++) {
            const float* wp = wic + (size_t)oc * CC * 9;  // uniform -> s_load
#pragma unroll
            for (int r = 0; r < 3; r++) {
                const float w0 = wp[r * 3 + 0];
                const float w1 = wp[r * 3 + 1];
                const float w2 = wp[r * 3 + 2];
#pragma unroll
                for (int q = 0; q < 8; q++)
                    acc[oc][q] = fmaf(w0, win[r][q],
                                 fmaf(w1, win[r][q + 1],
                                 fmaf(w2, win[r][q + 2], acc[oc][q])));
            }
        }
    }

    const size_t obase = ((size_t)b * CC + ocg * 8) * PLANE + (size_t)y * WW + x0;
#pragma unroll
    for (int oc = 0; oc < 8; oc++) {
        const float bv = bias[ocg * 8 + oc];
        float v[8];
#pragma unroll
        for (int q = 0; q < 8; q++) v[q] = acc[oc][q] + bv;
        if (do_prelu) {
            const float a = prelu[ocg * 8 + oc];
#pragma unroll
            for (int q = 0; q < 8; q++)
                v[q] = fmaxf(v[q], 0.f) + a * fminf(v[q], 0.f);
        }
        float* o = out + obase + (size_t)oc * PLANE;
        *(float4*)(o)     = make_float4(v[0], v[1], v[2], v[3]);
        *(float4*)(o + 4) = make_float4(v[4], v[5], v[6], v[7]);
    }
}

// ---------------- per-pixel channel mean/max ----------------
__global__ __launch_bounds__(256) void chanstats_kernel(
    const float* __restrict__ r, float* __restrict__ amx /*[B,2,HW]*/)
{
    int pix = blockIdx.x * 256 + threadIdx.x;
    int b = blockIdx.y;
    const float* rb = r + (size_t)b * CC * PLANE + pix;
    float s = 0.f, m = -INFINITY;
    for (int c = 0; c < CC; c++) {
        float v = rb[(size_t)c * PLANE];
        s += v; m = fmaxf(m, v);
    }
    amx[(size_t)b * 2 * PLANE + pix] = s * (1.f / CC);
    amx[(size_t)b * 2 * PLANE + PLANE + pix] = m;
}

// ---------------- global average pool: g[b,c] ----------------
__global__ __launch_bounds__(256) void gpool_kernel(
    const float* __restrict__ r, float* __restrict__ g /*[B*C]*/)
{
    int bc = blockIdx.x; // 0..511
    const float* p = r + (size_t)bc * PLANE;
    float s = 0.f;
    for (int i = threadIdx.x; i < PLANE; i += 256) s += p[i];
    for (int off = 32; off > 0; off >>= 1) s += __shfl_down(s, off, 64);
    __shared__ float ls[4];
    int lane = threadIdx.x & 63, wv = threadIdx.x >> 6;
    if (lane == 0) ls[wv] = s;
    __syncthreads();
    if (threadIdx.x == 0)
        g[bc] = (ls[0] + ls[1] + ls[2] + ls[3]) * (1.f / PLANE);
}

// ---------------- spatial-attention 3x3 conv (2ch -> 1ch) ----------------
__global__ __launch_bounds__(256) void saconv_kernel(
    const float* __restrict__ amx, const float* __restrict__ sa_w,
    const float* __restrict__ sa_b, float* __restrict__ smap)
{
    int pix = blockIdx.x * 256 + threadIdx.x;
    int b = blockIdx.y;
    int x = pix & 255, y = pix >> 8;
    float acc = sa_b[0];
    const float* ab = amx + (size_t)b * 2 * PLANE;
#pragma unroll
    for (int c = 0; c < 2; c++)
#pragma unroll
        for (int dy = -1; dy <= 1; dy++)
#pragma unroll
            for (int dx = -1; dx <= 1; dx++) {
                int gx = x + dx; gx = gx < 0 ? 1 : (gx >= WW ? 2 * WW - 2 - gx : gx);
                int gy = y + dy; gy = gy < 0 ? 1 : (gy >= HH ? 2 * HH - 2 - gy : gy);
                acc += sa_w[c * 9 + (dy + 1) * 3 + (dx + 1)] * ab[(size_t)c * PLANE + gy * WW + gx];
            }
    smap[(size_t)b * PLANE + pix] = acc;
}

// ---------------- tiny MLPs: channel attention + hyper kernels ----------------
__global__ __launch_bounds__(256) void mlp_kernel(
    const float* __restrict__ h, const float* __restrict__ g,
    const float* __restrict__ ca_w1, const float* __restrict__ ca_b1,
    const float* __restrict__ ca_a,
    const float* __restrict__ ca_w2, const float* __restrict__ ca_b2,
    const float* __restrict__ fc_w, const float* __restrict__ fc_b,
    const float* __restrict__ k1_w, const float* __restrict__ k1_b,
    const float* __restrict__ k2_w, const float* __restrict__ k2_b,
    const float* __restrict__ k3_w, const float* __restrict__ k3_b,
    float* __restrict__ kernA, float* __restrict__ kernB /*[B,64,64]*/)
{
    int b = blockIdx.x, tid = threadIdx.x;
    __shared__ float gb[64], t16[16], u32[32], v32[32], cg1[32], casig[64];

    if (tid < 64) gb[tid] = g[b * 64 + tid];
    __syncthreads();

    if (tid < 16) {
        float s = fc_b[tid];
        for (int j = 0; j < 16; j++) s += fc_w[tid * 16 + j] * h[b * 16 + j];
        t16[tid] = s >= 0.f ? s : 0.01f * s;
    }
    if (tid < 32) {
        float c1 = ca_b1[tid];
        for (int j = 0; j < 64; j++) c1 += ca_w1[tid * 64 + j] * gb[j];
        cg1[tid] = fmaxf(c1, 0.f) + ca_a[tid] * fminf(c1, 0.f);
    }
    __syncthreads();
    if (tid < 32) {
        float s = k1_b[tid];
        for (int j = 0; j < 16; j++) s += k1_w[tid * 16 + j] * t16[j];
        u32[tid] = s >= 0.f ? s : 0.01f * s;
    }
    if (tid < 64) {
        float c2 = ca_b2[tid];
        for (int j = 0; j < 32; j++) c2 += ca_w2[tid * 32 + j] * cg1[j];
        casig[tid] = 1.f / (1.f + expf(-c2));
    }
    __syncthreads();
    if (tid < 32) {
        float s = k2_b[tid];
        for (int j = 0; j < 32; j++) s += k2_w[tid * 32 + j] * u32[j];
        v32[tid] = s >= 0.f ? s : 0.01f * s;
    }
    __syncthreads();
    // k3: 8192 outputs x 32 MACs; fold casig into the ca half
    for (int o = tid; o < 8192; o += 256) {
        float s = k3_b[o];
        for (int j = 0; j < 32; j++) s += k3_w[(size_t)o * 32 + j] * v32[j];
        int oc = o >> 7;       // /128
        int i = o & 127;
        if (i < 64) kernA[((size_t)b * 64 + oc) * 64 + i] = s;
        else        kernB[((size_t)b * 64 + oc) * 64 + (i - 64)] = s * casig[i - 64];
    }
}

// ---------------- final: out = x + hc_bias + sig(s)*(A.r) + (B.r) ----------------
__global__ __launch_bounds__(256) void final_kernel(
    const float* __restrict__ x, const float* __restrict__ r,
    const float* __restrict__ smap,
    const float* __restrict__ kernA, const float* __restrict__ kernB,
    const float* __restrict__ hc_bias,
    float* __restrict__ out)
{
    const int tid = threadIdx.x;
    const int pix = blockIdx.x * 256 + tid;
    const int og = blockIdx.y * 32;   // oc group: 0 or 32
    const int b = blockIdx.z;

    __shared__ float kA[64][32], kB[64][32]; // transposed [c][oc], 16 KiB
    for (int idx = tid; idx < 64 * 32; idx += 256) {
        int oc = idx & 31, c = idx >> 5;
        kA[c][oc] = kernA[((size_t)b * 64 + og + oc) * 64 + c];
        kB[c][oc] = kernB[((size_t)b * 64 + og + oc) * 64 + c];
    }
    __syncthreads();

    float accA[32], accB[32];
#pragma unroll
    for (int i = 0; i < 32; i++) { accA[i] = 0.f; accB[i] = 0.f; }

    const float* rb = r + (size_t)b * CC * PLANE + pix;
    for (int c = 0; c < CC; c++) {
        float rv = rb[(size_t)c * PLANE];
#pragma unroll
        for (int oc = 0; oc < 32; oc++) {
            accA[oc] += kA[c][oc] * rv;
            accB[oc] += kB[c][oc] * rv;
        }
    }

    float sv = smap[(size_t)b * PLANE + pix];
    float sig = 1.f / (1.f + expf(-sv));
    const float* xb = x + ((size_t)b * CC + og) * PLANE + pix;
    float* ob = out + ((size_t)b * CC + og) * PLANE + pix;
#pragma unroll
    for (int oc = 0; oc < 32; oc++) {
        ob[(size_t)oc * PLANE] = xb[(size_t)oc * PLANE] + hc_bias[og + oc]
                               + sig * accA[oc] + accB[oc];
    }
}

extern "C" void kernel_launch(void* const* d_in, const int* in_sizes, int n_in,
                              void* d_out, int out_size, void* d_ws, size_t ws_size,
                              hipStream_t stream) {
    const float* x   = (const float*)d_in[0];
    const float* h   = (const float*)d_in[1];
    const float* c1w = (const float*)d_in[2];
    const float* c1b = (const float*)d_in[3];
    const float* pa  = (const float*)d_in[4];
    const float* c2w = (const float*)d_in[5];
    const float* c2b = (const float*)d_in[6];
    const float* saw = (const float*)d_in[7];
    const float* sab = (const float*)d_in[8];
    const float* cw1 = (const float*)d_in[9];
    const float* cb1 = (const float*)d_in[10];
    const float* caa = (const float*)d_in[11];
    const float* cw2 = (const float*)d_in[12];
    const float* cb2 = (const float*)d_in[13];
    const float* fcw = (const float*)d_in[14];
    const float* fcb = (const float*)d_in[15];
    const float* k1w = (const float*)d_in[16];
    const float* k1b = (const float*)d_in[17];
    const float* k2w = (const float*)d_in[18];
    const float* k2b = (const float*)d_in[19];
    const float* k3w = (const float*)d_in[20];
    const float* k3b = (const float*)d_in[21];
    const float* hcb = (const float*)d_in[22];
    float* out = (float*)d_out;

    char* ws = (char*)d_ws;
    const size_t SZ_R = (size_t)8 * CC * PLANE * sizeof(float); // 134,217,728
    float* r1 = (float*)ws;
    float* r  = (float*)(ws + SZ_R);
    // r1 is dead after conv2 — reuse its space for the small buffers
    float* amx   = (float*)ws;                                    // 8*2*65536 f
    float* smap  = (float*)(ws + (size_t)8 * 2 * PLANE * 4);      // 8*65536 f
    float* g     = (float*)(ws + (size_t)8 * 3 * PLANE * 4);      // 512 f
    float* kernA = (float*)(ws + (size_t)8 * 3 * PLANE * 4 + 4096);
    float* kernB = kernA + (size_t)8 * 64 * 64;

    dim3 cgrid(HH / 8, CC / 8, 8); // (32 ytiles, 8 oc-groups, 8 batch)
    conv3x3_kernel<<<cgrid, 256, 0, stream>>>(x, c1w, c1b, pa, r1, 1);
    conv3x3_kernel<<<cgrid, 256, 0, stream>>>(r1, c2w, c2b, nullptr, r, 0);

    chanstats_kernel<<<dim3(PLANE / 256, 8), 256, 0, stream>>>(r, amx);
    gpool_kernel<<<512, 256, 0, stream>>>(r, g);
    saconv_kernel<<<dim3(PLANE / 256, 8), 256, 0, stream>>>(amx, saw, sab, smap);
    mlp_kernel<<<8, 256, 0, stream>>>(h, g, cw1, cb1, caa, cw2, cb2,
                                      fcw, fcb, k1w, k1b, k2w, k2b, k3w, k3b,
                                      kernA, kernB);
    final_kernel<<<dim3(PLANE / 256, 2, 8), 256, 0, stream>>>(
        x, r, smap, kernA, kernB, hcb, out);
}